// Round 8
// baseline (92.619 us; speedup 1.0000x reference)
//
#include <hip/hip_runtime.h>

#define NFREQ   257
#define NFRAMES 3751
#define NS      480000
#define HOP     128
#define WIN     512

#define NB      32
#define BN      256                 // frames per block
#define NFT     15                  // frame tiles (15*256 = 3840)
#define STEPS   16                  // 2 fpairs * 8 ks (freq rows 0..255; Nyquist in tail)

#define XWPITCH 272                 // padded row stride (128 samples + 16B pad)
#define XWROWS  259                 // (BN-1)*HOP + WIN = 33152 samples
#define XW_B    70448               // 259*272
#define AHALF   32768               // one A buffer: R 16KB + I 16KB (128 rows x 128B)
#define WNYQ_B  1024
#define XGROUPS 4144                // 33152/8 16B-groups

typedef __attribute__((ext_vector_type(8))) short short8;
typedef __attribute__((ext_vector_type(4))) float f32x4;

__device__ __forceinline__ short f2bf(float f) {
    __bf16 b = (__bf16)f;
    return __builtin_bit_cast(short, b);
}

__device__ __forceinline__ float bf2f(short s) {
    unsigned int u = ((unsigned int)(unsigned short)s) << 16;
    return __builtin_bit_cast(float, u);
}

__device__ __forceinline__ void gload_lds16(const void* g, void* l) {
    __builtin_amdgcn_global_load_lds(
        (const __attribute__((address_space(1))) void*)g,
        (__attribute__((address_space(3))) void*)l,
        16, 0, 0);
}

// ---- prep: bake per-step A staging stream (swizzle included) + nyq row ----
// abL: 16 steps x 32KB. Step s, chunk c (0..2047, 16B each):
//   plane = c>>10, r = (c>>3)&127, colg = c&7
//   LDS image offset = plane*16384 + r*128 + colg*16  (written linearly as c*16)
//   holds basis[plane, fr=(s>>3)*128+r], elements starting at
//   kel = ((s&7)*128 + ((colg*16) ^ ((r&7)<<4)))/2
__global__ __launch_bounds__(256)
void prep_basis2(const float* __restrict__ basis,
                 short* __restrict__ abL, short* __restrict__ wnyqG) {
    int g = blockIdx.x * 256 + threadIdx.x;
    if (g < 32768) {
        int s    = g >> 11;
        int c    = g & 2047;
        int plane = c >> 10;
        int r    = (c >> 3) & 127;
        int colg = c & 7;
        int fr   = (s >> 3) * 128 + r;                      // 0..255
        int kel  = (((s & 7) * 128 + ((colg * 16) ^ ((r & 7) << 4))) >> 1);
        const float4* p = reinterpret_cast<const float4*>(
            basis + ((size_t)(plane * NFREQ + fr)) * WIN + kel);
        float4 a0 = p[0], a1 = p[1];
        short8 v;
        v[0]=f2bf(a0.x); v[1]=f2bf(a0.y); v[2]=f2bf(a0.z); v[3]=f2bf(a0.w);
        v[4]=f2bf(a1.x); v[5]=f2bf(a1.y); v[6]=f2bf(a1.z); v[7]=f2bf(a1.w);
        *reinterpret_cast<short8*>(reinterpret_cast<char*>(abL) + (size_t)g * 16) = v;
    } else if (g < 32832) {                                 // nyq row: real plane row 256
        int j = g - 32768;
        const float4* p = reinterpret_cast<const float4*>(
            basis + (size_t)256 * WIN + j * 8);
        float4 a0 = p[0], a1 = p[1];
        short8 v;
        v[0]=f2bf(a0.x); v[1]=f2bf(a0.y); v[2]=f2bf(a0.z); v[3]=f2bf(a0.w);
        v[4]=f2bf(a1.x); v[5]=f2bf(a1.y); v[6]=f2bf(a1.z); v[7]=f2bf(a1.w);
        *reinterpret_cast<short8*>(wnyqG + j * 8) = v;
    }
}

// ---- main: 512 thr, 8 waves (2 freq x 4 frame), 128x256 tile, wave tile 64x64 ----
__global__ __launch_bounds__(512, 2)
void stft_mfma_kernel(const float* __restrict__ x,
                      const short* __restrict__ abL,
                      const short* __restrict__ wnyqG,
                      float* __restrict__ out)
{
    __shared__ __align__(16) char smem[XW_B + 2 * AHALF + WNYQ_B];  // 137008 B
    char* const xw   = smem;
    char* const aBuf = smem + XW_B;
    char* const wnyq = smem + XW_B + 2 * AHALF;

    const int tid  = threadIdx.x;
    const int wave = tid >> 6;
    const int lane = tid & 63;
    const int wr   = wave >> 2;          // wave freq row (0..1) -> 64 rows
    const int wc   = wave & 3;           // wave frame col (0..3) -> 64 frames
    const int lgrp = lane >> 4;
    const int l15  = lane & 15;

    // bijective XCD chunk swizzle: 480 = 8 * 60
    const int logical = (blockIdx.x & 7) * 60 + (blockIdx.x >> 3);
    const int ft = logical % NFT;
    const int b  = logical / NFT;
    const int t0 = ft * BN;

    const char* abLc = (const char*)abL;

    // ---- prologue A: step-0 stage (2048 chunks, 4/thread) + nyq weights ----
    #pragma unroll
    for (int i = 0; i < 4; ++i) {
        int c = wave * 256 + i * 64 + lane;
        gload_lds16(abLc + (size_t)c * 16, aBuf + c * 16);
    }
    if (wave == 0)
        gload_lds16((const char*)wnyqG + lane * 16, wnyq);

    // ---- prologue X: fp32 window -> bf16, padded rows, reflect at edges ----
    {
        const float* __restrict__ xb = x + (size_t)b * NS;
        const int sbase = t0 * 128 - 256;          // unpadded index of window sample 0
        #pragma unroll
        for (int i = 0; i < 9; ++i) {
            int g = tid + i * 512;                 // 16B (8-sample) group
            if (g < XGROUPS) {
                int ix = sbase + g * 8;
                short8 v;
                if (ix >= 0 && ix + 8 <= NS) {     // interior fast path
                    const float4* p = reinterpret_cast<const float4*>(xb + ix);
                    float4 a0 = p[0], a1 = p[1];
                    v[0]=f2bf(a0.x); v[1]=f2bf(a0.y); v[2]=f2bf(a0.z); v[3]=f2bf(a0.w);
                    v[4]=f2bf(a1.x); v[5]=f2bf(a1.y); v[6]=f2bf(a1.z); v[7]=f2bf(a1.w);
                } else {
                    #pragma unroll
                    for (int q = 0; q < 8; ++q) {
                        int idx = ix + q;
                        if (idx < 0) idx = -idx;
                        if (idx >= NS + 256) { v[q] = 0; continue; }  // zero slack
                        if (idx >= NS) idx = 2 * NS - 2 - idx;        // reflect
                        v[q] = f2bf(xb[idx]);
                    }
                }
                *reinterpret_cast<short8*>(xw + (g >> 4) * XWPITCH + (g & 15) * 16) = v;
            }
        }
    }

    f32x4 accR[4][4], accI[4][4];
    #pragma unroll
    for (int m = 0; m < 4; ++m)
        #pragma unroll
        for (int nt = 0; nt < 4; ++nt) {
            accR[m][nt] = f32x4{0.f, 0.f, 0.f, 0.f};
            accI[m][nt] = f32x4{0.f, 0.f, 0.f, 0.f};
        }

    const int tlb = (wc * 64 + l15) * XWPITCH;     // X row base for this lane

    #pragma unroll 1
    for (int s = 0; s < STEPS; ++s) {
        // stage(s) loads landed; all waves' ds_writes/loads visible after barrier
        asm volatile("s_waitcnt vmcnt(0)" ::: "memory");
        __builtin_amdgcn_sched_barrier(0);
        __syncthreads();
        __builtin_amdgcn_sched_barrier(0);

        char* const aCur = aBuf + (s & 1) * AHALF;

        // ---- issue NEXT A stage into the other buffer (overlaps compute) ----
        if (s + 1 < STEPS) {
            char* const aNxt = aBuf + ((s + 1) & 1) * AHALF;
            const char* sb = abLc + (size_t)(s + 1) * 32768;
            #pragma unroll
            for (int i = 0; i < 4; ++i) {
                int c = wave * 256 + i * 64 + lane;
                gload_lds16(sb + (size_t)c * 16, aNxt + c * 16);
            }
        }
        __builtin_amdgcn_sched_barrier(0);   // pin: stage issue precedes compute

        // ---- compute current step (K=64: two 32-k halves) ----
        const int ksb2 = (s & 7) * 128;
        #pragma unroll
        for (int ko = 0; ko < 2; ++ko) {
            const int kb = ko * 64 + lgrp * 16;
            short8 aRv[4], aIv[4], xv[4];
            #pragma unroll
            for (int m = 0; m < 4; ++m) {
                int row = wr * 64 + m * 16 + l15;
                int o = row * 128 + (kb ^ ((row & 7) << 4));
                aRv[m] = *reinterpret_cast<const short8*>(aCur + o);
                aIv[m] = *reinterpret_cast<const short8*>(aCur + 16384 + o);
            }
            {
                int r8 = ksb2 + kb;                      // 0..1008 (byte col)
                int T  = r8 + ((r8 >> 4) & 0x30);        // padded-row remap
                #pragma unroll
                for (int nt = 0; nt < 4; ++nt)
                    xv[nt] = *reinterpret_cast<const short8*>(xw + tlb + nt * (16 * XWPITCH) + T);
            }
            #pragma unroll
            for (int m = 0; m < 4; ++m)
                #pragma unroll
                for (int nt = 0; nt < 4; ++nt) {
                    accR[m][nt] = __builtin_amdgcn_mfma_f32_16x16x32_bf16(aRv[m], xv[nt], accR[m][nt], 0, 0, 0);
                    accI[m][nt] = __builtin_amdgcn_mfma_f32_16x16x32_bf16(aIv[m], xv[nt], accI[m][nt], 0, 0, 0);
                }
        }

        // ---- per-fpair epilogue (after ks=7); f = fpair*128 + 0..127 < 257 ----
        if ((s & 7) == 7) {
            const int fp = s >> 3;
            const int fBase = fp * 128 + wr * 64 + lgrp * 4;
            const int tBase = t0 + wc * 64 + l15;
            float* ob = out + (size_t)b * NFREQ * NFRAMES;
            #pragma unroll
            for (int m = 0; m < 4; ++m)
                #pragma unroll
                for (int nt = 0; nt < 4; ++nt) {
                    int t = tBase + nt * 16;
                    if (t < NFRAMES) {
                        #pragma unroll
                        for (int r = 0; r < 4; ++r) {
                            int f = fBase + m * 16 + r;
                            float vr = accR[m][nt][r], vi = accI[m][nt][r];
                            ob[(size_t)f * NFRAMES + t] = sqrtf(vr * vr + vi * vi);
                        }
                    }
                    accR[m][nt] = f32x4{0.f, 0.f, 0.f, 0.f};
                    accI[m][nt] = f32x4{0.f, 0.f, 0.f, 0.f};
                }
        }
    }

    // ---- Nyquist tail: f=256, |dot(x_frame, w)|; x & w already in LDS ----
    {
        const int fl = wave * 32 + (lane & 31);       // local frame 0..255
        const int h  = lane >> 5;                     // half of the 512-window
        const int xbase = (fl + 2 * h) * XWPITCH;
        const int wbase = h * 512;
        float acc = 0.f;
        #pragma unroll
        for (int j = 0; j < 32; ++j) {
            short8 xv8 = *reinterpret_cast<const short8*>(
                xw + xbase + (j >> 4) * XWPITCH + (j & 15) * 16);
            short8 wv8 = *reinterpret_cast<const short8*>(wnyq + wbase + j * 16);
            #pragma unroll
            for (int q = 0; q < 8; ++q)
                acc = fmaf(bf2f(xv8[q]), bf2f(wv8[q]), acc);
        }
        acc += __shfl_xor(acc, 32);
        int t = t0 + fl;
        if (h == 0 && t < NFRAMES)
            out[((size_t)b * NFREQ + 256) * NFRAMES + t] = fabsf(acc);
    }
}

extern "C" void kernel_launch(void* const* d_in, const int* in_sizes, int n_in,
                              void* d_out, int out_size, void* d_ws, size_t ws_size,
                              hipStream_t stream) {
    const float* x     = (const float*)d_in[0];
    const float* basis = (const float*)d_in[1];
    float* out = (float*)d_out;

    short* abL   = (short*)d_ws;                       // 16 steps x 32KB = 512KB
    short* wnyqG = abL + 262144;                       // 512 bf16

    prep_basis2<<<dim3(129), 256, 0, stream>>>(basis, abL, wnyqG);
    stft_mfma_kernel<<<dim3(NFT * NB), 512, 0, stream>>>(x, abL, wnyqG, out);  // 480 blocks
}